// Round 3
// baseline (61.171 us; speedup 1.0000x reference)
//
#include <hip/hip_runtime.h>
#include <cmath>

// Problem constants
#define SS 2048
#define BB 32
#define HH 1024

typedef float __attribute__((ext_vector_type(4))) f32x4;  // native vector: ok for nontemporal builtins

// ---------------------------------------------------------------------------
// K1a: partial u[h] over 16-wide k-chunks: partial[c][h] = sum_{k in chunk c}
//      v[k] * We[k][h],  We[k][h] = attn_W[k][HH + h]
// grid (4, 64), block 256 -> 256 blocks, 16KB read each
// ---------------------------------------------------------------------------
__global__ __launch_bounds__(256) void partial_u_kernel(
    const float* __restrict__ W, const float* __restrict__ v,
    float* __restrict__ partial) {
  int h  = blockIdx.x * 256 + threadIdx.x;  // 0..1023
  int k0 = blockIdx.y * 16;
  float acc = 0.f;
#pragma unroll
  for (int k = k0; k < k0 + 16; ++k)
    acc += v[k] * W[(size_t)k * (2 * HH) + HH + h];
  partial[blockIdx.y * HH + h] = acc;
}

// K1b: u[h] = sum of 64 partials (deterministic, fixed order)
__global__ __launch_bounds__(256) void reduce_u_kernel(
    const float* __restrict__ partial, float* __restrict__ u) {
  int h = blockIdx.x * 256 + threadIdx.x;
  float acc = 0.f;
#pragma unroll
  for (int c = 0; c < 64; ++c) acc += partial[c * HH + h];
  u[h] = acc;
}

// ---------------------------------------------------------------------------
// K2: energy[b*S + s] = dot(enc[s,b,:], u)   -- the 256 MiB streaming kernel
// One wave per TWO consecutive rows (row = s*B + b). u fragment loaded once
// into registers and reused for both rows; enc reads nontemporal (pure
// stream, no reuse). 8 float4 loads in flight per lane.
// ---------------------------------------------------------------------------
__global__ __launch_bounds__(256) void energy_kernel(
    const float* __restrict__ enc, const float* __restrict__ u,
    float* __restrict__ energy) {
  int wave = blockIdx.x * 4 + (threadIdx.x >> 6);  // 0 .. S*B/2 - 1
  int lane = threadIdx.x & 63;
  int row0 = wave * 2;

  const f32x4* u4 = reinterpret_cast<const f32x4*>(u);
  f32x4 uv[4];
#pragma unroll
  for (int j = 0; j < 4; ++j) uv[j] = u4[lane + j * 64];

  const f32x4* e0 = reinterpret_cast<const f32x4*>(enc) + (size_t)row0 * (HH / 4);
  const f32x4* e1 = e0 + (HH / 4);

  float acc0 = 0.f, acc1 = 0.f;
#pragma unroll
  for (int j = 0; j < 4; ++j) {
    f32x4 a = __builtin_nontemporal_load(&e0[lane + j * 64]);
    f32x4 b = __builtin_nontemporal_load(&e1[lane + j * 64]);
    acc0 += a.x * uv[j].x + a.y * uv[j].y + a.z * uv[j].z + a.w * uv[j].w;
    acc1 += b.x * uv[j].x + b.y * uv[j].y + b.z * uv[j].z + b.w * uv[j].w;
  }
#pragma unroll
  for (int m = 32; m; m >>= 1) {
    acc0 += __shfl_xor(acc0, m, 64);
    acc1 += __shfl_xor(acc1, m, 64);
  }
  if (lane == 0) {
    int s0 = row0 / BB, b0 = row0 % BB;
    int s1 = (row0 + 1) / BB, b1 = (row0 + 1) % BB;
    energy[(size_t)b0 * SS + s0] = acc0;
    energy[(size_t)b1 * SS + s1] = acc1;
  }
}

// ---------------------------------------------------------------------------
// K3: in-place row softmax on d_out: 32 rows of 2048. One block per row.
// ---------------------------------------------------------------------------
__global__ __launch_bounds__(256) void softmax_kernel(float* __restrict__ e) {
  int b = blockIdx.x;
  float* row = e + (size_t)b * SS;
  int tid  = threadIdx.x;
  int lane = tid & 63;
  int wv   = tid >> 6;

  float vals[8];
  float mx = -INFINITY;
#pragma unroll
  for (int i = 0; i < 8; ++i) {
    vals[i] = row[tid + i * 256];
    mx = fmaxf(mx, vals[i]);
  }
#pragma unroll
  for (int m = 32; m; m >>= 1) mx = fmaxf(mx, __shfl_xor(mx, m, 64));

  __shared__ float red_max[4];
  __shared__ float red_sum[4];
  if (lane == 0) red_max[wv] = mx;
  __syncthreads();
  mx = fmaxf(fmaxf(red_max[0], red_max[1]), fmaxf(red_max[2], red_max[3]));

  float sum = 0.f;
#pragma unroll
  for (int i = 0; i < 8; ++i) {
    vals[i] = expf(vals[i] - mx);
    sum += vals[i];
  }
#pragma unroll
  for (int m = 32; m; m >>= 1) sum += __shfl_xor(sum, m, 64);
  if (lane == 0) red_sum[wv] = sum;
  __syncthreads();
  sum = red_sum[0] + red_sum[1] + red_sum[2] + red_sum[3];

  float inv = 1.0f / sum;
#pragma unroll
  for (int i = 0; i < 8; ++i) row[tid + i * 256] = vals[i] * inv;
}

extern "C" void kernel_launch(void* const* d_in, const int* in_sizes, int n_in,
                              void* d_out, int out_size, void* d_ws, size_t ws_size,
                              hipStream_t stream) {
  const float* enc = (const float*)d_in[0];   // (S,B,H)
  // d_in[1] rnn_hidden, d_in[3] attn_b: cancel under softmax (shift-invariant)
  const float* W = (const float*)d_in[2];     // (H, 2H)
  const float* v = (const float*)d_in[4];     // (1, H)
  float* out = (float*)d_out;                 // (B,1,S) = B*S floats

  float* u       = (float*)d_ws;              // 4 KB
  float* partial = (float*)d_ws + HH;         // 256 KB

  partial_u_kernel<<<dim3(4, 64), 256, 0, stream>>>(W, v, partial);
  reduce_u_kernel<<<4, 256, 0, stream>>>(partial, u);
  energy_kernel<<<(SS * BB) / 8, 256, 0, stream>>>(enc, u, out);
  softmax_kernel<<<BB, 256, 0, stream>>>(out);
}